// Round 16
// baseline (122.896 us; speedup 1.0000x reference)
//
#include <hip/hip_runtime.h>
#include <hip/hip_bf16.h>

#define NN 50000
#define NE 1600000
#define D  128
#define NB   500            // coarse buckets (500 so grid fills 256 CUs at 2 blk/CU)
#define NPB  100            // nodes per bucket
#define RCAP 4224           // region capacity per bucket (mean 3200 + 18 sigma)
#define ECH  6250           // edges per k_bucket block (256 * 6250 = NE)

typedef unsigned int u32;
typedef unsigned long long u64;
typedef unsigned short u16;
typedef __attribute__((ext_vector_type(8))) short short8;
typedef __attribute__((ext_vector_type(4))) float f32x4;
typedef __attribute__((ext_vector_type(2))) float f32x2;

// ws layout (bytes):
//   gcur u32[NB]       @ 0          (memset 0)
//   flag int           @ 2048       (memset 0)
//   region u32[NB*RCAP]@ 4096       (8.45 MB)
//   xf8  fp8[(NN+1)*D] @ 8452096    (6.4 MB) e4m3; row NN = zeros
#define GCUR_OFF 0
#define FLAG_OFF 2048
#define REG_OFF  4096
#define XF8_OFF  8452096

__device__ __forceinline__ u32 pack2(float a, float b) {   // 2x f32 -> bf16 RNE
    u32 ua = __float_as_uint(a), ub = __float_as_uint(b);
    ua = (ua + 0x7FFFu + ((ua >> 16) & 1u)) >> 16;
    ub = (ub + 0x7FFFu + ((ub >> 16) & 1u)) >> 16;
    return ua | (ub << 16);
}

// ---------------------------------------------------------------------------
__global__ __launch_bounds__(256) void k_detect(const int* __restrict__ ei,
                                                int* __restrict__ flag) {
    int local = 0;
    for (int i = threadIdx.x; i < 2048; i += 256)
        if (ei[2 * i + 1] == 0) local++;
    if (local) atomicAdd(flag, local);
}

// ---------------------------------------------------------------------------
__global__ __launch_bounds__(64) void k_zrow(u32* __restrict__ xzrow) {
    if (threadIdx.x < 32) xzrow[threadIdx.x] = 0u;   // fp8 0x00 == 0.0f
}

// ---------------------------------------------------------------------------
// x (f32) -> xf8 (fp8 e4m3, 4/word), coalesced.
__global__ __launch_bounds__(256) void k_cast(const float* __restrict__ x,
                                              uint2* __restrict__ xf8) {
    const int total = NN * D / 8;  // 800000
    for (int i = blockIdx.x * 256 + threadIdx.x; i < total; i += gridDim.x * 256) {
        const float4 a = reinterpret_cast<const float4*>(x)[2 * i];
        const float4 b = reinterpret_cast<const float4*>(x)[2 * i + 1];
        uint2 o;
        o.x = (u32)__builtin_amdgcn_cvt_pk_fp8_f32(a.z, a.w,
                 __builtin_amdgcn_cvt_pk_fp8_f32(a.x, a.y, 0, false), true);
        o.y = (u32)__builtin_amdgcn_cvt_pk_fp8_f32(b.z, b.w,
                 __builtin_amdgcn_cvt_pk_fp8_f32(b.x, b.y, 0, false), true);
        xf8[i] = o;
    }
}

// ---------------------------------------------------------------------------
// Bucket scatter: block groups its 6250-edge chunk by coarse bucket (512 bins,
// two-level scan) in LDS, reserves one contiguous global run per
// (block,bucket) with ONE atomicAdd, writes runs coalesced.
// Entry = (bucket<<23)|(dst_local<<16)|src  (9+7+16 bits).
__global__ __launch_bounds__(256) void k_bucket(const int* __restrict__ ei,
                                                const int* __restrict__ flag,
                                                u32* __restrict__ gcur,
                                                u32* __restrict__ region) {
    __shared__ u32 eL[ECH + 6];      // staged entries
    __shared__ u32 srt[ECH + 6];     // bucket-grouped entries
    __shared__ u32 lh[512], sc[512], gb[512], lc[512];
    __shared__ u32 ps[256];

    const int t = threadIdx.x;
    const bool is64 = (*flag > 1024);
    const int e0 = blockIdx.x * ECH;

    lh[t] = 0u; lh[t + 256] = 0u; lc[t] = 0u; lc[t + 256] = 0u;
    __syncthreads();

    // Phase A: load + histogram
    for (int i = t; i < ECH; i += 256) {
        const int e = e0 + i;
        int src, dst;
        if (is64) { src = ei[2 * (size_t)e]; dst = ei[2 * (size_t)(NE + e)]; }
        else      { src = ei[e];             dst = ei[NE + e]; }
        const u32 b2 = (u32)dst / NPB;
        const u32 dl = (u32)dst - b2 * NPB;
        eL[i] = (b2 << 23) | (dl << 16) | (u32)src;
        atomicAdd(&lh[b2], 1u);
    }
    __syncthreads();

    // two-level inclusive scan over 512 bins (pair sums -> 256-wide scan)
    const u32 a0 = lh[2 * t], a1 = lh[2 * t + 1];
    ps[t] = a0 + a1;
    __syncthreads();
    for (int ofs = 1; ofs < 256; ofs <<= 1) {
        const u32 v = (t >= ofs) ? ps[t - ofs] : 0u;
        __syncthreads();
        ps[t] += v;
        __syncthreads();
    }
    const u32 base = ps[t] - (a0 + a1);
    sc[2 * t]     = base + a0;           // inclusive
    sc[2 * t + 1] = base + a0 + a1;
    // reserve global runs (bins 2t, 2t+1)
    if (a0) gb[2 * t]     = atomicAdd(&gcur[2 * t],     a0);
    if (a1) gb[2 * t + 1] = atomicAdd(&gcur[2 * t + 1], a1);
    __syncthreads();

    // Phase B: group by bucket in LDS
    for (int i = t; i < ECH; i += 256) {
        const u32 e = eL[i];
        const u32 b2 = e >> 23;
        const u32 lp = atomicAdd(&lc[b2], 1u);
        srt[(sc[b2] - lh[b2]) + lp] = e;
    }
    __syncthreads();

    // Phase C: wave-parallel coalesced copy of bucket runs
    const int w4  = t >> 6;
    const int l64 = t & 63;
    for (int b2 = w4; b2 < NB; b2 += 4) {
        const int len = (int)lh[b2];
        if (!len) continue;
        const u32 lb0 = sc[b2] - lh[b2];
        const u32 g0  = gb[b2];
        u32* dst = region + (size_t)b2 * RCAP;
        for (int i = l64; i < len; i += 64) {
            const u32 pos = g0 + (u32)i;
            if (pos < RCAP) dst[pos] = srt[lb0 + i];
        }
    }
}

// ---------------------------------------------------------------------------
// Aggregate: one block (1024 thr) per bucket, 500 blocks -> ~2 blocks/CU
// (round 15 fix: occupancy was GRID-limited at 250 blocks, not LDS-limited).
// Sort bucket's edges by dst (128-bin hist+scan+scatter, integer LDS atomics),
// then atomic-free register gather, 8 edges/iter (4 loads in flight per lane).
#define GLOAD(J) \
    const int  i##J = i + 2 * J + half; \
    const u32 ev##J = srt[i##J]; \
    const u32 sr##J = (i##J < s1) ? (ev##J & 0xFFFFu) : (u32)NN; \
    const u32 wv##J = xf8[(size_t)sr##J * 32 + q];

#define GACC(J) { \
    const f32x2 lo = __builtin_amdgcn_cvt_pk_f32_fp8((int)wv##J, false); \
    const f32x2 hi = __builtin_amdgcn_cvt_pk_f32_fp8((int)wv##J, true); \
    a01 += lo; a23 += hi; }

__global__ __launch_bounds__(1024, 8) void k_agg(const u32* __restrict__ xf8,
                                                 const u32* __restrict__ region,
                                                 const u32* __restrict__ gcur,
                                                 float* __restrict__ mean) {
    __shared__ u32 srt[RCAP + 8];    // ~16.9 KB dst-sorted entries (+pad)
    __shared__ u32 hist[128], segs[128], cur[128];

    const int t = threadIdx.x;
    const int b = blockIdx.x;

    if (t < 128) { hist[t] = 0u; cur[t] = 0u; }
    __syncthreads();

    u32 cnt = gcur[b];
    if (cnt > RCAP) cnt = RCAP;
    const u32* reg = region + (size_t)b * RCAP;

    // pass 1: histogram (coalesced global read, integer LDS atomics)
    for (int i = t; i < (int)cnt; i += 1024)
        atomicAdd(&hist[(reg[i] >> 16) & 0x7Fu], 1u);
    __syncthreads();

    // inclusive scan of 128 bins on first 128 threads
    if (t < 128) segs[t] = hist[t];
    __syncthreads();
    for (int ofs = 1; ofs < 128; ofs <<= 1) {
        u32 v = 0u;
        if (t < 128 && t >= ofs) v = segs[t - ofs];
        __syncthreads();
        if (t < 128) segs[t] += v;
        __syncthreads();
    }

    // pass 2: scatter into dst-sorted LDS order (second coalesced global read)
    for (int i = t; i < (int)cnt; i += 1024) {
        const u32 e = reg[i];
        const u32 dl = (e >> 16) & 0x7Fu;
        const u32 p = (segs[dl] - hist[dl]) + atomicAdd(&cur[dl], 1u);
        srt[p] = e;
    }
    if (t < 8) srt[cnt + t] = (u32)NN;   // pad (reads beyond s1 are select-guarded)
    __syncthreads();

    // per-node register gather: 8 edges/iter, 4 loads in flight per lane
    const int w    = t >> 6;        // 0..15
    const int lane = t & 63;
    const int half = lane >> 5;
    const u32 q    = (u32)(lane & 31);
    const int row0 = b * NPB;

    for (int r = w; r < NPB; r += 16) {
        const int deg = (int)hist[r];
        const int s1  = (int)segs[r];
        const int s0  = s1 - deg;

        f32x2 a01 = {0.f, 0.f}, a23 = {0.f, 0.f};
        for (int i = s0; i < s1; i += 8) {
            GLOAD(0) GLOAD(1) GLOAD(2) GLOAD(3)    // 4 independent row loads
            GACC(0) GACC(1) GACC(2) GACC(3)
        }

        const float r0 = a01.x + __shfl_xor(a01.x, 32);
        const float r1 = a01.y + __shfl_xor(a01.y, 32);
        const float r2 = a23.x + __shfl_xor(a23.x, 32);
        const float r3 = a23.y + __shfl_xor(a23.y, 32);

        if (lane < 32) {
            const float inv = deg ? 1.0f / (float)deg : 0.0f;
            float4 o;
            o.x = r0 * inv; o.y = r1 * inv; o.z = r2 * inv; o.w = r3 * inv;
            *reinterpret_cast<float4*>(mean + (size_t)(row0 + r) * D + q * 4) = o;
        }
    }
}

// ---------------------------------------------------------------------------
// MFMA GEMM: out = relu([mean|x] @ [Wl|Wr]^T + bl), K=256, bf16 in, f32 acc.
// io = d_out: mean rows read into LDS per 16-row group, then overwritten.
__global__ __launch_bounds__(256) void k_gemm(const float* __restrict__ Wl,
                                              const float* __restrict__ Wr,
                                              const float* __restrict__ bl,
                                              const float* __restrict__ x,
                                              float* __restrict__ io) {
    __shared__ u16 Bs[128 * 256];  // [j][k] bf16, byte ^= (j&7)<<4
    __shared__ u16 As[16 * 256];   // [m][k] bf16, byte ^= (m&7)<<4

    const int t = threadIdx.x;

    for (int s = t; s < 4096; s += 256) {
        const int mat = s >> 11;
        const int j   = (s >> 4) & 127;
        const int k8  = (s & 15) * 8;
        const float* src = (mat ? Wr : Wl) + (size_t)j * 128 + k8;
        const float4 a = reinterpret_cast<const float4*>(src)[0];
        const float4 b = reinterpret_cast<const float4*>(src)[1];
        uint4 o;
        o.x = pack2(a.x, a.y); o.y = pack2(a.z, a.w);
        o.z = pack2(b.x, b.y); o.w = pack2(b.z, b.w);
        const u32 byte = ((u32)(j * 512 + (mat * 128 + k8) * 2)) ^ ((u32)(j & 7) << 4);
        *reinterpret_cast<uint4*>(reinterpret_cast<char*>(Bs) + byte) = o;
    }

    const int lane = t & 63;
    const int wv   = t >> 6;
    const int m16  = lane & 15;
    const int kg   = lane >> 4;

    for (int g = blockIdx.x; g < NN / 16; g += gridDim.x) {
        const int row0 = g * 16;
        __syncthreads();
        {
            const int m  = t >> 4;
            const int k8 = (t & 15) * 8;
            const float* srcm = io + (size_t)(row0 + m) * D + k8;
            float4 a = reinterpret_cast<const float4*>(srcm)[0];
            float4 b = reinterpret_cast<const float4*>(srcm)[1];
            uint4 o;
            o.x = pack2(a.x, a.y); o.y = pack2(a.z, a.w);
            o.z = pack2(b.x, b.y); o.w = pack2(b.z, b.w);
            const u32 byte = ((u32)(m * 512 + k8 * 2)) ^ ((u32)(m & 7) << 4);
            *reinterpret_cast<uint4*>(reinterpret_cast<char*>(As) + byte) = o;

            const float* srcx = x + (size_t)(row0 + m) * D + k8;
            a = reinterpret_cast<const float4*>(srcx)[0];
            b = reinterpret_cast<const float4*>(srcx)[1];
            o.x = pack2(a.x, a.y); o.y = pack2(a.z, a.w);
            o.z = pack2(b.x, b.y); o.w = pack2(b.z, b.w);
            const u32 byte2 = ((u32)(m * 512 + (128 + k8) * 2)) ^ ((u32)(m & 7) << 4);
            *reinterpret_cast<uint4*>(reinterpret_cast<char*>(As) + byte2) = o;
        }
        __syncthreads();

        f32x4 acc0 = {0.f, 0.f, 0.f, 0.f};
        f32x4 acc1 = {0.f, 0.f, 0.f, 0.f};
        const int j0 = wv * 32 + m16;
        const int j1 = j0 + 16;
        #pragma unroll
        for (int ks = 0; ks < 8; ks++) {
            const int k = ks * 32 + kg * 8;
            const u32 ab  = ((u32)(m16 * 512 + k * 2)) ^ ((u32)(m16 & 7) << 4);
            const u32 bb0 = ((u32)(j0  * 512 + k * 2)) ^ ((u32)(j0  & 7) << 4);
            const u32 bb1 = ((u32)(j1  * 512 + k * 2)) ^ ((u32)(j1  & 7) << 4);
            const short8 af  = *reinterpret_cast<const short8*>(reinterpret_cast<const char*>(As) + ab);
            const short8 bf0 = *reinterpret_cast<const short8*>(reinterpret_cast<const char*>(Bs) + bb0);
            const short8 bf1 = *reinterpret_cast<const short8*>(reinterpret_cast<const char*>(Bs) + bb1);
            acc0 = __builtin_amdgcn_mfma_f32_16x16x32_bf16(af, bf0, acc0, 0, 0, 0);
            acc1 = __builtin_amdgcn_mfma_f32_16x16x32_bf16(af, bf1, acc1, 0, 0, 0);
        }

        const float bias0 = bl[wv * 32 + m16];
        const float bias1 = bl[wv * 32 + 16 + m16];
        #pragma unroll
        for (int i = 0; i < 4; i++) {
            const int r = kg * 4 + i;
            float* orow = io + (size_t)(row0 + r) * D;
            orow[wv * 32 + m16]      = fmaxf(acc0[i] + bias0, 0.f);
            orow[wv * 32 + 16 + m16] = fmaxf(acc1[i] + bias1, 0.f);
        }
    }
}

// ---------------------------------------------------------------------------
extern "C" void kernel_launch(void* const* d_in, const int* in_sizes, int n_in,
                              void* d_out, int out_size, void* d_ws, size_t ws_size,
                              hipStream_t stream) {
    const float* x  = (const float*)d_in[0];
    const int*   ei = (const int*)  d_in[1];
    const float* Wl = (const float*)d_in[2];
    const float* bl = (const float*)d_in[3];
    const float* Wr = (const float*)d_in[4];

    char* ws = (char*)d_ws;
    u32*   gcur   = (u32*)(ws + GCUR_OFF);
    int*   flag   = (int*)(ws + FLAG_OFF);
    u32*   region = (u32*)(ws + REG_OFF);
    u32*   xf8    = (u32*)(ws + XF8_OFF);
    float* out    = (float*)d_out;

    hipMemsetAsync(ws, 0, 4096, stream);    // gcur + flag
    k_detect<<<1, 256, 0, stream>>>(ei, flag);
    k_zrow  <<<1, 64, 0, stream>>>(xf8 + (size_t)NN * 32);
    k_cast  <<<2048, 256, 0, stream>>>(x, (uint2*)xf8);
    k_bucket<<<256, 256, 0, stream>>>(ei, flag, gcur, region);
    k_agg   <<<NB, 1024, 0, stream>>>(xf8, region, gcur, out);
    k_gemm  <<<1024, 256, 0, stream>>>(Wl, Wr, bl, x, out);
}

// Round 17
// 99.922 us; speedup vs baseline: 1.2299x; 1.2299x over previous
//
#include <hip/hip_runtime.h>
#include <hip/hip_bf16.h>

#define NN 50000
#define NE 1600000
#define D  128
#define NB   500            // coarse buckets (grid fills 256 CUs at ~2 blk/CU)
#define NPB  100            // nodes per bucket
#define RCAP 4224           // region capacity per bucket (mean 3200 + 18 sigma)
#define ECH  6250           // edges per k_bucket block (256 * 6250 = NE)

typedef unsigned int u32;
typedef unsigned long long u64;
typedef unsigned short u16;
typedef __attribute__((ext_vector_type(8))) short short8;
typedef __attribute__((ext_vector_type(4))) float f32x4;
typedef __attribute__((ext_vector_type(2))) float f32x2;

// ws layout (bytes):
//   gcur u32[NB]       @ 0          (memset 0)
//   flag int           @ 2048       (memset 0)
//   region u32[NB*RCAP]@ 4096       (8.45 MB)
//   xf8  fp8[(NN+1)*D] @ 8452096    (6.4 MB) e4m3; row NN = zeros
#define GCUR_OFF 0
#define FLAG_OFF 2048
#define REG_OFF  4096
#define XF8_OFF  8452096

__device__ __forceinline__ u32 pack2(float a, float b) {   // 2x f32 -> bf16 RNE
    u32 ua = __float_as_uint(a), ub = __float_as_uint(b);
    ua = (ua + 0x7FFFu + ((ua >> 16) & 1u)) >> 16;
    ub = (ub + 0x7FFFu + ((ub >> 16) & 1u)) >> 16;
    return ua | (ub << 16);
}

// ---------------------------------------------------------------------------
__global__ __launch_bounds__(256) void k_detect(const int* __restrict__ ei,
                                                int* __restrict__ flag) {
    int local = 0;
    for (int i = threadIdx.x; i < 2048; i += 256)
        if (ei[2 * i + 1] == 0) local++;
    if (local) atomicAdd(flag, local);
}

// ---------------------------------------------------------------------------
__global__ __launch_bounds__(64) void k_zrow(u32* __restrict__ xzrow) {
    if (threadIdx.x < 32) xzrow[threadIdx.x] = 0u;   // fp8 0x00 == 0.0f
}

// ---------------------------------------------------------------------------
// x (f32) -> xf8 (fp8 e4m3, 4/word), coalesced.
__global__ __launch_bounds__(256) void k_cast(const float* __restrict__ x,
                                              uint2* __restrict__ xf8) {
    const int total = NN * D / 8;  // 800000
    for (int i = blockIdx.x * 256 + threadIdx.x; i < total; i += gridDim.x * 256) {
        const float4 a = reinterpret_cast<const float4*>(x)[2 * i];
        const float4 b = reinterpret_cast<const float4*>(x)[2 * i + 1];
        uint2 o;
        o.x = (u32)__builtin_amdgcn_cvt_pk_fp8_f32(a.z, a.w,
                 __builtin_amdgcn_cvt_pk_fp8_f32(a.x, a.y, 0, false), true);
        o.y = (u32)__builtin_amdgcn_cvt_pk_fp8_f32(b.z, b.w,
                 __builtin_amdgcn_cvt_pk_fp8_f32(b.x, b.y, 0, false), true);
        xf8[i] = o;
    }
}

// ---------------------------------------------------------------------------
// Bucket scatter: block groups its 6250-edge chunk by coarse bucket (512 bins,
// two-level scan) in LDS, reserves one contiguous global run per
// (block,bucket) with ONE atomicAdd, then FLAT entry-parallel copy (round 16
// fix: per-wave bucket loops were 80% idle at run length 12.5).
// Entry = (bucket<<23)|(dst_local<<16)|src  (9+7+16 bits).
__global__ __launch_bounds__(256) void k_bucket(const int* __restrict__ ei,
                                                const int* __restrict__ flag,
                                                u32* __restrict__ gcur,
                                                u32* __restrict__ region) {
    __shared__ u32 eL[ECH + 6];      // staged entries
    __shared__ u32 srt[ECH + 6];     // bucket-grouped entries
    __shared__ u32 lh[512], sc[512], gb[512], lc[512];
    __shared__ u32 ps[256];

    const int t = threadIdx.x;
    const bool is64 = (*flag > 1024);
    const int e0 = blockIdx.x * ECH;

    lh[t] = 0u; lh[t + 256] = 0u; lc[t] = 0u; lc[t + 256] = 0u;
    __syncthreads();

    // Phase A: load + histogram
    for (int i = t; i < ECH; i += 256) {
        const int e = e0 + i;
        int src, dst;
        if (is64) { src = ei[2 * (size_t)e]; dst = ei[2 * (size_t)(NE + e)]; }
        else      { src = ei[e];             dst = ei[NE + e]; }
        const u32 b2 = (u32)dst / NPB;
        const u32 dl = (u32)dst - b2 * NPB;
        eL[i] = (b2 << 23) | (dl << 16) | (u32)src;
        atomicAdd(&lh[b2], 1u);
    }
    __syncthreads();

    // two-level inclusive scan over 512 bins (pair sums -> 256-wide scan)
    const u32 a0 = lh[2 * t], a1 = lh[2 * t + 1];
    ps[t] = a0 + a1;
    __syncthreads();
    for (int ofs = 1; ofs < 256; ofs <<= 1) {
        const u32 v = (t >= ofs) ? ps[t - ofs] : 0u;
        __syncthreads();
        ps[t] += v;
        __syncthreads();
    }
    const u32 base = ps[t] - (a0 + a1);
    sc[2 * t]     = base + a0;           // inclusive
    sc[2 * t + 1] = base + a0 + a1;
    // reserve global runs (bins 2t, 2t+1)
    if (a0) gb[2 * t]     = atomicAdd(&gcur[2 * t],     a0);
    if (a1) gb[2 * t + 1] = atomicAdd(&gcur[2 * t + 1], a1);
    __syncthreads();

    // Phase B: group by bucket in LDS
    for (int i = t; i < ECH; i += 256) {
        const u32 e = eL[i];
        const u32 b2 = e >> 23;
        const u32 lp = atomicAdd(&lc[b2], 1u);
        srt[(sc[b2] - lh[b2]) + lp] = e;
    }
    __syncthreads();

    // Phase C: flat entry-parallel copy — every thread busy every iteration.
    // srt is bucket-contiguous: global pos = gb[b2] + (i - run_start).
    for (int i = t; i < ECH; i += 256) {
        const u32 e   = srt[i];
        const u32 b2  = e >> 23;
        const u32 run0 = sc[b2] - lh[b2];
        const u32 pos  = gb[b2] + ((u32)i - run0);
        if (pos < RCAP) region[(size_t)b2 * RCAP + pos] = e;
    }
}

// ---------------------------------------------------------------------------
// Aggregate: one block (1024 thr) per bucket, 500 blocks -> ~2 blocks/CU.
// Sort bucket's edges by dst (128-bin hist+scan+scatter, integer LDS atomics),
// then atomic-free register gather, 8 edges/iter (4 loads in flight per lane).
#define GLOAD(J) \
    const int  i##J = i + 2 * J + half; \
    const u32 ev##J = srt[i##J]; \
    const u32 sr##J = (i##J < s1) ? (ev##J & 0xFFFFu) : (u32)NN; \
    const u32 wv##J = xf8[(size_t)sr##J * 32 + q];

#define GACC(J) { \
    const f32x2 lo = __builtin_amdgcn_cvt_pk_f32_fp8((int)wv##J, false); \
    const f32x2 hi = __builtin_amdgcn_cvt_pk_f32_fp8((int)wv##J, true); \
    a01 += lo; a23 += hi; }

__global__ __launch_bounds__(1024, 8) void k_agg(const u32* __restrict__ xf8,
                                                 const u32* __restrict__ region,
                                                 const u32* __restrict__ gcur,
                                                 float* __restrict__ mean) {
    __shared__ u32 srt[RCAP + 8];    // ~16.9 KB dst-sorted entries (+pad)
    __shared__ u32 hist[128], segs[128], cur[128];

    const int t = threadIdx.x;
    const int b = blockIdx.x;

    if (t < 128) { hist[t] = 0u; cur[t] = 0u; }
    __syncthreads();

    u32 cnt = gcur[b];
    if (cnt > RCAP) cnt = RCAP;
    const u32* reg = region + (size_t)b * RCAP;

    // pass 1: histogram (coalesced global read, integer LDS atomics)
    for (int i = t; i < (int)cnt; i += 1024)
        atomicAdd(&hist[(reg[i] >> 16) & 0x7Fu], 1u);
    __syncthreads();

    // inclusive scan of 128 bins on first 128 threads
    if (t < 128) segs[t] = hist[t];
    __syncthreads();
    for (int ofs = 1; ofs < 128; ofs <<= 1) {
        u32 v = 0u;
        if (t < 128 && t >= ofs) v = segs[t - ofs];
        __syncthreads();
        if (t < 128) segs[t] += v;
        __syncthreads();
    }

    // pass 2: scatter into dst-sorted LDS order (second coalesced global read)
    for (int i = t; i < (int)cnt; i += 1024) {
        const u32 e = reg[i];
        const u32 dl = (e >> 16) & 0x7Fu;
        const u32 p = (segs[dl] - hist[dl]) + atomicAdd(&cur[dl], 1u);
        srt[p] = e;
    }
    if (t < 8) srt[cnt + t] = (u32)NN;   // pad (reads beyond s1 are select-guarded)
    __syncthreads();

    // per-node register gather: 8 edges/iter, 4 loads in flight per lane
    const int w    = t >> 6;        // 0..15
    const int lane = t & 63;
    const int half = lane >> 5;
    const u32 q    = (u32)(lane & 31);
    const int row0 = b * NPB;

    for (int r = w; r < NPB; r += 16) {
        const int deg = (int)hist[r];
        const int s1  = (int)segs[r];
        const int s0  = s1 - deg;

        f32x2 a01 = {0.f, 0.f}, a23 = {0.f, 0.f};
        for (int i = s0; i < s1; i += 8) {
            GLOAD(0) GLOAD(1) GLOAD(2) GLOAD(3)    // 4 independent row loads
            GACC(0) GACC(1) GACC(2) GACC(3)
        }

        const float r0 = a01.x + __shfl_xor(a01.x, 32);
        const float r1 = a01.y + __shfl_xor(a01.y, 32);
        const float r2 = a23.x + __shfl_xor(a23.x, 32);
        const float r3 = a23.y + __shfl_xor(a23.y, 32);

        if (lane < 32) {
            const float inv = deg ? 1.0f / (float)deg : 0.0f;
            float4 o;
            o.x = r0 * inv; o.y = r1 * inv; o.z = r2 * inv; o.w = r3 * inv;
            *reinterpret_cast<float4*>(mean + (size_t)(row0 + r) * D + q * 4) = o;
        }
    }
}

// ---------------------------------------------------------------------------
// MFMA GEMM: out = relu([mean|x] @ [Wl|Wr]^T + bl), K=256, bf16 in, f32 acc.
// io = d_out: mean rows read into LDS per 16-row group, then overwritten.
__global__ __launch_bounds__(256) void k_gemm(const float* __restrict__ Wl,
                                              const float* __restrict__ Wr,
                                              const float* __restrict__ bl,
                                              const float* __restrict__ x,
                                              float* __restrict__ io) {
    __shared__ u16 Bs[128 * 256];  // [j][k] bf16, byte ^= (j&7)<<4
    __shared__ u16 As[16 * 256];   // [m][k] bf16, byte ^= (m&7)<<4

    const int t = threadIdx.x;

    for (int s = t; s < 4096; s += 256) {
        const int mat = s >> 11;
        const int j   = (s >> 4) & 127;
        const int k8  = (s & 15) * 8;
        const float* src = (mat ? Wr : Wl) + (size_t)j * 128 + k8;
        const float4 a = reinterpret_cast<const float4*>(src)[0];
        const float4 b = reinterpret_cast<const float4*>(src)[1];
        uint4 o;
        o.x = pack2(a.x, a.y); o.y = pack2(a.z, a.w);
        o.z = pack2(b.x, b.y); o.w = pack2(b.z, b.w);
        const u32 byte = ((u32)(j * 512 + (mat * 128 + k8) * 2)) ^ ((u32)(j & 7) << 4);
        *reinterpret_cast<uint4*>(reinterpret_cast<char*>(Bs) + byte) = o;
    }

    const int lane = t & 63;
    const int wv   = t >> 6;
    const int m16  = lane & 15;
    const int kg   = lane >> 4;

    for (int g = blockIdx.x; g < NN / 16; g += gridDim.x) {
        const int row0 = g * 16;
        __syncthreads();
        {
            const int m  = t >> 4;
            const int k8 = (t & 15) * 8;
            const float* srcm = io + (size_t)(row0 + m) * D + k8;
            float4 a = reinterpret_cast<const float4*>(srcm)[0];
            float4 b = reinterpret_cast<const float4*>(srcm)[1];
            uint4 o;
            o.x = pack2(a.x, a.y); o.y = pack2(a.z, a.w);
            o.z = pack2(b.x, b.y); o.w = pack2(b.z, b.w);
            const u32 byte = ((u32)(m * 512 + k8 * 2)) ^ ((u32)(m & 7) << 4);
            *reinterpret_cast<uint4*>(reinterpret_cast<char*>(As) + byte) = o;

            const float* srcx = x + (size_t)(row0 + m) * D + k8;
            a = reinterpret_cast<const float4*>(srcx)[0];
            b = reinterpret_cast<const float4*>(srcx)[1];
            o.x = pack2(a.x, a.y); o.y = pack2(a.z, a.w);
            o.z = pack2(b.x, b.y); o.w = pack2(b.z, b.w);
            const u32 byte2 = ((u32)(m * 512 + (128 + k8) * 2)) ^ ((u32)(m & 7) << 4);
            *reinterpret_cast<uint4*>(reinterpret_cast<char*>(As) + byte2) = o;
        }
        __syncthreads();

        f32x4 acc0 = {0.f, 0.f, 0.f, 0.f};
        f32x4 acc1 = {0.f, 0.f, 0.f, 0.f};
        const int j0 = wv * 32 + m16;
        const int j1 = j0 + 16;
        #pragma unroll
        for (int ks = 0; ks < 8; ks++) {
            const int k = ks * 32 + kg * 8;
            const u32 ab  = ((u32)(m16 * 512 + k * 2)) ^ ((u32)(m16 & 7) << 4);
            const u32 bb0 = ((u32)(j0  * 512 + k * 2)) ^ ((u32)(j0  & 7) << 4);
            const u32 bb1 = ((u32)(j1  * 512 + k * 2)) ^ ((u32)(j1  & 7) << 4);
            const short8 af  = *reinterpret_cast<const short8*>(reinterpret_cast<const char*>(As) + ab);
            const short8 bf0 = *reinterpret_cast<const short8*>(reinterpret_cast<const char*>(Bs) + bb0);
            const short8 bf1 = *reinterpret_cast<const short8*>(reinterpret_cast<const char*>(Bs) + bb1);
            acc0 = __builtin_amdgcn_mfma_f32_16x16x32_bf16(af, bf0, acc0, 0, 0, 0);
            acc1 = __builtin_amdgcn_mfma_f32_16x16x32_bf16(af, bf1, acc1, 0, 0, 0);
        }

        const float bias0 = bl[wv * 32 + m16];
        const float bias1 = bl[wv * 32 + 16 + m16];
        #pragma unroll
        for (int i = 0; i < 4; i++) {
            const int r = kg * 4 + i;
            float* orow = io + (size_t)(row0 + r) * D;
            orow[wv * 32 + m16]      = fmaxf(acc0[i] + bias0, 0.f);
            orow[wv * 32 + 16 + m16] = fmaxf(acc1[i] + bias1, 0.f);
        }
    }
}

// ---------------------------------------------------------------------------
extern "C" void kernel_launch(void* const* d_in, const int* in_sizes, int n_in,
                              void* d_out, int out_size, void* d_ws, size_t ws_size,
                              hipStream_t stream) {
    const float* x  = (const float*)d_in[0];
    const int*   ei = (const int*)  d_in[1];
    const float* Wl = (const float*)d_in[2];
    const float* bl = (const float*)d_in[3];
    const float* Wr = (const float*)d_in[4];

    char* ws = (char*)d_ws;
    u32*   gcur   = (u32*)(ws + GCUR_OFF);
    int*   flag   = (int*)(ws + FLAG_OFF);
    u32*   region = (u32*)(ws + REG_OFF);
    u32*   xf8    = (u32*)(ws + XF8_OFF);
    float* out    = (float*)d_out;

    hipMemsetAsync(ws, 0, 4096, stream);    // gcur + flag
    k_detect<<<1, 256, 0, stream>>>(ei, flag);
    k_zrow  <<<1, 64, 0, stream>>>(xf8 + (size_t)NN * 32);
    k_cast  <<<2048, 256, 0, stream>>>(x, (uint2*)xf8);
    k_bucket<<<256, 256, 0, stream>>>(ei, flag, gcur, region);
    k_agg   <<<NB, 1024, 0, stream>>>(xf8, region, gcur, out);
    k_gemm  <<<1024, 256, 0, stream>>>(Wl, Wr, bl, x, out);
}